// Round 2
// baseline (1080.596 us; speedup 1.0000x reference)
//
#include <hip/hip_runtime.h>
#include <math.h>

#define N_IMG 16
#define CIN   64
#define CMID  128
#define CO    32
#define KHD   16
#define HL    128
#define WL    128
#define HO    256
#define WO    256
#define EPSV  1e-5f

// ---------------- workspace layout (floats) ----------------
// [0, 33554432)            t (16,128,128,128)       -- dead after K3
// [33554432, 50331648)     refodd (16,16,256,256)   -- K5 overwrites IN PLACE with gx
// [50331648, +2048)        S1
// [+2048, +2048)           S2
// [+..., 65536)            w2effT (16,128,32)  [n][c][o]
// [+..., 512)              beff (16,32)
// total 50,401,744 floats = 201.6 MB  (< 256 MB ws)
// gy lives in d_out (K6 reads gy[idx] before writing out[idx] in-thread).

// K1: t[n][o][y][x] = conv1_b[o] + sum_c conv1_w[o][c] * lo[n][c][y][x]
__global__ __launch_bounds__(256) void k1_conv1(const float* __restrict__ lo,
                                                const float* __restrict__ w1,
                                                const float* __restrict__ b1,
                                                float* __restrict__ t) {
  int blk = blockIdx.x;        // n*128 + y
  int n = blk >> 7, y = blk & 127;
  __shared__ float lo_l[CIN * WL];    // [c][x]  32 KB
  __shared__ float w1_l[CMID * CIN];  // [o][c]  32 KB
  int tid = threadIdx.x;
  const float* lo_base = lo + (size_t)n * CIN * (HL * WL) + y * WL;
  for (int f = tid; f < CIN * WL / 4; f += 256) {
    int c = f >> 5, xi = f & 31;
    ((float4*)lo_l)[f] = *(const float4*)(lo_base + (size_t)c * (HL * WL) + xi * 4);
  }
  for (int f = tid; f < CMID * CIN / 4; f += 256)
    ((float4*)w1_l)[f] = ((const float4*)w1)[f];
  __syncthreads();

  int pg = tid & 31, og = tid >> 5;  // 32 pixel-groups(x4) x 8 out-groups(x16)
  float acc[16][4];
#pragma unroll
  for (int oo = 0; oo < 16; ++oo)
    acc[oo][0] = acc[oo][1] = acc[oo][2] = acc[oo][3] = 0.f;

  for (int c = 0; c < CIN; c += 4) {
    float4 v0 = *(float4*)&lo_l[(c + 0) * WL + pg * 4];
    float4 v1 = *(float4*)&lo_l[(c + 1) * WL + pg * 4];
    float4 v2 = *(float4*)&lo_l[(c + 2) * WL + pg * 4];
    float4 v3 = *(float4*)&lo_l[(c + 3) * WL + pg * 4];
#pragma unroll
    for (int oo = 0; oo < 16; ++oo) {
      float4 w = *(float4*)&w1_l[(og * 16 + oo) * CIN + c];
      acc[oo][0] += w.x * v0.x + w.y * v1.x + w.z * v2.x + w.w * v3.x;
      acc[oo][1] += w.x * v0.y + w.y * v1.y + w.z * v2.y + w.w * v3.y;
      acc[oo][2] += w.x * v0.z + w.y * v1.z + w.z * v2.z + w.w * v3.z;
      acc[oo][3] += w.x * v0.w + w.y * v1.w + w.z * v2.w + w.w * v3.w;
    }
  }
#pragma unroll
  for (int oo = 0; oo < 16; ++oo) {
    int o = og * 16 + oo;
    float bb = b1[o];
    float4 r;
    r.x = acc[oo][0] + bb; r.y = acc[oo][1] + bb;
    r.z = acc[oo][2] + bb; r.w = acc[oo][3] + bb;
    *(float4*)(t + (((size_t)n * CMID + o) * HL + y) * WL + pg * 4) = r;
  }
}

__device__ __forceinline__ float gelu_exact(float v) {
  return 0.5f * v * (1.f + erff(v * 0.70710678118654752f));
}

// K2: per (n,c): sum & sumsq of GELU(bilinear_upsample(t[n,c])) over 256x256
__global__ __launch_bounds__(256) void k2_stats(const float* __restrict__ t,
                                                float* __restrict__ S1,
                                                float* __restrict__ S2) {
  int blk = blockIdx.x;  // n*128 + c
  __shared__ float img[HL * WL];  // exactly 64 KB; [0..15] reused for reduction
  int tid = threadIdx.x;
  const float* tb = t + (size_t)blk * (HL * WL);
  for (int f = tid; f < HL * WL / 4; f += 256)
    ((float4*)img)[f] = ((const float4*)tb)[f];
  __syncthreads();

  float xs = tid * (127.f / 255.f);
  float x0f = floorf(xs);
  int x0 = (int)x0f, x1 = min(x0 + 1, 127);
  float wx = xs - x0f, omwx = 1.f - wx;
  float sum = 0.f, ssq = 0.f;
  for (int i = 0; i < HO; ++i) {
    float ys = i * (127.f / 255.f);
    float y0f = floorf(ys);
    int y0 = (int)y0f, y1 = min(y0 + 1, 127);
    float wy = ys - y0f, omwy = 1.f - wy;
    float r0 = img[y0 * WL + x0] * omwx + img[y0 * WL + x1] * wx;
    float r1 = img[y1 * WL + x0] * omwx + img[y1 * WL + x1] * wx;
    float g = gelu_exact(r0 * omwy + r1 * wy);
    sum += g; ssq += g * g;
  }
  int lane = tid & 63, w = tid >> 6;
#pragma unroll
  for (int d = 32; d; d >>= 1) {
    sum += __shfl_xor(sum, d, 64);
    ssq += __shfl_xor(ssq, d, 64);
  }
  __syncthreads();  // everyone done reading img
  if (lane == 0) { img[w] = sum; img[8 + w] = ssq; }
  __syncthreads();
  if (tid == 0) {
    S1[blk] = img[0] + img[1] + img[2] + img[3];
    S2[blk] = img[8] + img[9] + img[10] + img[11];
  }
}

// K2b: fold GN + SE + conv2 into per-image effective weights (transposed [c][o]) + bias
__global__ __launch_bounds__(128) void k2b_prep(const float* __restrict__ S1,
                                                const float* __restrict__ S2,
                                                const float* __restrict__ gn_w,
                                                const float* __restrict__ gn_b,
                                                const float* __restrict__ se_w1,
                                                const float* __restrict__ se_w2,
                                                const float* __restrict__ w2,
                                                float* __restrict__ w2effT,
                                                float* __restrict__ beff) {
  int n = blockIdx.x, c = threadIdx.x;
  __shared__ float mArr[128], eArr[128], pArr[128], hArr[16], dArr[128];
  const float inv = 1.f / 65536.f;
  float m = S1[n * 128 + c] * inv, e2 = S2[n * 128 + c] * inv;
  mArr[c] = m; eArr[c] = e2;
  __syncthreads();
  int g0 = (c >> 6) << 6;
  float mu = 0.f, E2 = 0.f;
  for (int q = 0; q < 64; ++q) { mu += mArr[g0 + q]; E2 += eArr[g0 + q]; }
  mu *= (1.f / 64.f); E2 *= (1.f / 64.f);
  float var = E2 - mu * mu;
  float rs = rsqrtf(var + EPSV);
  float gw = gn_w[c], gb = gn_b[c];
  pArr[c] = (m - mu) * rs * gw + gb;
  __syncthreads();
  if (c < 16) {
    float h = 0.f;
    for (int q = 0; q < 128; ++q) h += se_w1[c * 128 + q] * pArr[q];
    hArr[c] = fmaxf(h, 0.f);
  }
  __syncthreads();
  float sacc = 0.f;
  for (int q = 0; q < 16; ++q) sacc += se_w2[c * 16 + q] * hArr[q];
  float s = 1.f / (1.f + __expf(-sacc));
  float a = s * gw * rs;
  float d = s * (gb - gw * rs * mu);
  dArr[c] = d;
  __syncthreads();
  for (int o = 0; o < 32; ++o)
    w2effT[((size_t)n * 128 + c) * 32 + o] = w2[o * 128 + c] * a;
  if (c < 32) {
    float bb = 0.f;
    for (int q = 0; q < 128; ++q) bb += w2[c * 128 + q] * dArr[q];
    beff[n * 32 + c] = bb;
  }
}

// K3: per (n, output-row i): recompute r = GELU(upsample(t)), acc = W2eff . r + beff,
//     then row softmax+cumsum of even channels -> gy (in d_out); odd channels -> refodd
__global__ __launch_bounds__(256) void k3_ref(const float* __restrict__ t,
                                              const float* __restrict__ w2effT,
                                              const float* __restrict__ beff,
                                              float* __restrict__ refodd,
                                              float* __restrict__ gy) {
  int blk = blockIdx.x;  // n*256 + i
  int n = blk >> 8, i = blk & 255;
  __shared__ float wlT[CMID * CO];      // [c][o] 16 KB
  __shared__ float bl[CO];
  __shared__ float ch[32 * 2 * WL];     // [cc][row][x] 32 KB
  __shared__ float sred[4], ssum[4];
  int tid = threadIdx.x;
  for (int f = tid; f < CMID * CO / 4; f += 256)
    ((float4*)wlT)[f] = ((const float4*)(w2effT + (size_t)n * CMID * CO))[f];
  if (tid < 32) bl[tid] = beff[n * 32 + tid];

  float ys = i * (127.f / 255.f);
  float y0f = floorf(ys);
  int y0 = (int)y0f, y1 = min(y0 + 1, 127);
  float wy = ys - y0f, omwy = 1.f - wy;
  float xs = tid * (127.f / 255.f);
  float x0f = floorf(xs);
  int x0 = (int)x0f, x1 = min(x0 + 1, 127);
  float wx = xs - x0f, omwx = 1.f - wx;

  float acc[32];
#pragma unroll
  for (int o = 0; o < 32; ++o) acc[o] = 0.f;

  const size_t tbase = (size_t)n * CMID * (HL * WL);
  for (int cb = 0; cb < 4; ++cb) {
    __syncthreads();
    for (int f = tid; f < 32 * 2 * WL / 4; f += 256) {
      int cc = f >> 6, rem = f & 63;
      int row = rem >> 5, xi = rem & 31;
      int yy = row ? y1 : y0;
      ((float4*)ch)[f] =
          *(const float4*)(t + tbase + ((size_t)(cb * 32 + cc) * HL + yy) * WL + xi * 4);
    }
    __syncthreads();
#pragma unroll 4
    for (int cc = 0; cc < 32; ++cc) {
      const float* c0 = &ch[cc * 2 * WL];
      float v0 = c0[x0] * omwx + c0[x1] * wx;
      float v1 = c0[WL + x0] * omwx + c0[WL + x1] * wx;
      float g = gelu_exact(v0 * omwy + v1 * wy);
      const float* wrow = &wlT[(cb * 32 + cc) * 32];
#pragma unroll
      for (int o4 = 0; o4 < 8; ++o4) {
        float4 w4 = *(const float4*)&wrow[o4 * 4];
        acc[o4 * 4 + 0] += w4.x * g;
        acc[o4 * 4 + 1] += w4.y * g;
        acc[o4 * 4 + 2] += w4.z * g;
        acc[o4 * 4 + 3] += w4.w * g;
      }
    }
  }
#pragma unroll
  for (int o = 0; o < 32; ++o) acc[o] += bl[o];

  // odd channels: materialize for the column-scan kernel
#pragma unroll
  for (int k = 0; k < 16; ++k)
    refodd[(((size_t)(n * 16 + k)) * HO + i) * WO + tid] = acc[2 * k + 1];

  // even channels: row softmax + inclusive cumsum -> gy = cumsum/total * 255
  int lane = tid & 63, w = tid >> 6;
  for (int k = 0; k < 16; ++k) {
    float v = acc[2 * k];
    float m = v;
#pragma unroll
    for (int d = 32; d; d >>= 1) m = fmaxf(m, __shfl_xor(m, d, 64));
    if (lane == 0) sred[w] = m;
    __syncthreads();
    m = fmaxf(fmaxf(sred[0], sred[1]), fmaxf(sred[2], sred[3]));
    float p = __expf(v - m);
#pragma unroll
    for (int d = 1; d < 64; d <<= 1) {
      float q = __shfl_up(p, d, 64);
      if (lane >= d) p += q;
    }
    if (lane == 63) ssum[w] = p;
    __syncthreads();
    float off = 0.f, tot = 0.f;
#pragma unroll
    for (int q = 0; q < 4; ++q) {
      float x = ssum[q];
      tot += x;
      if (q < w) off += x;
    }
    gy[((size_t)(n * 16 + k) * HO + i) * WO + tid] = (p + off) / tot * 255.f;
    __syncthreads();
  }
}

// K5: per (n,k): column softmax+cumsum of odd channel -> gx IN PLACE over refodd
__global__ __launch_bounds__(256) void k5_colscan(float* __restrict__ refodd) {
  int nk = blockIdx.x;
  int j = threadIdx.x;
  float* img = refodd + (size_t)nk * (HO * WO);
  float m = -1e30f;
  for (int i = 0; i < HO; ++i) m = fmaxf(m, img[i * WO + j]);
  float s = 0.f;
  for (int i = 0; i < HO; ++i) s += __expf(img[i * WO + j] - m);
  float run = 0.f;
  for (int i = 0; i < HO; ++i) {
    float v = img[i * WO + j];        // read before overwrite (same thread)
    run += __expf(v - m);
    img[i * WO + j] = run / s * 255.f;
  }
}

// K6: bilinear grid sample with zeros padding, align_corners=True (coords pre-scaled to pixels)
// NOTE: gy aliases out — each thread reads gy[idx] before writing out[idx].
__global__ __launch_bounds__(256) void k6_sample(const float* __restrict__ gx,
                                                 const float* __restrict__ gy,
                                                 const float* __restrict__ hi,
                                                 float* __restrict__ out) {
  size_t idx = (size_t)blockIdx.x * 256 + threadIdx.x;
  int nk = blockIdx.x >> 8;
  const float* img = hi + (size_t)nk * (HO * WO);
  float gxv = gx[idx], gyv = gy[idx];
  float x0f = floorf(gxv), y0f = floorf(gyv);
  float wx = gxv - x0f, wy = gyv - y0f;
  float omwx = 1.f - wx, omwy = 1.f - wy;

  float r = 0.f;
#pragma unroll
  for (int cy = 0; cy < 2; ++cy) {
#pragma unroll
    for (int cx = 0; cx < 2; ++cx) {
      float xf = x0f + cx, yf = y0f + cy;
      bool valid = (xf >= 0.f) && (xf <= 255.f) && (yf >= 0.f) && (yf <= 255.f);
      float wgt = (cx ? wx : omwx) * (cy ? wy : omwy);
      if (valid) {
        int xi = (int)xf, yi = (int)yf;
        r += img[yi * WO + xi] * wgt;
      }
    }
  }
  out[idx] = r;
}

extern "C" void kernel_launch(void* const* d_in, const int* in_sizes, int n_in,
                              void* d_out, int out_size, void* d_ws, size_t ws_size,
                              hipStream_t stream) {
  (void)in_sizes; (void)n_in; (void)out_size; (void)ws_size;
  const float* lo  = (const float*)d_in[0];
  const float* hi  = (const float*)d_in[1];
  const float* w1  = (const float*)d_in[2];
  const float* b1  = (const float*)d_in[3];
  const float* gnw = (const float*)d_in[4];
  const float* gnb = (const float*)d_in[5];
  const float* sw1 = (const float*)d_in[6];
  const float* sw2 = (const float*)d_in[7];
  const float* w2  = (const float*)d_in[8];
  float* ws = (float*)d_ws;
  float* t       = ws;                    // 33,554,432 floats
  float* refodd  = ws + 33554432;         // 16,777,216 floats (becomes gx in-place)
  float* S1      = ws + 50331648;         // 2048
  float* S2      = S1 + 2048;             // 2048
  float* w2effT  = S2 + 2048;             // 65,536
  float* beff    = w2effT + 65536;        // 512
  float* out     = (float*)d_out;
  float* gybuf   = out;                   // gy aliases d_out (read-before-write in K6)

  k1_conv1<<<dim3(2048), dim3(256), 0, stream>>>(lo, w1, b1, t);
  k2_stats<<<dim3(2048), dim3(256), 0, stream>>>(t, S1, S2);
  k2b_prep<<<dim3(16), dim3(128), 0, stream>>>(S1, S2, gnw, gnb, sw1, sw2, w2, w2effT, beff);
  k3_ref<<<dim3(4096), dim3(256), 0, stream>>>(t, w2effT, beff, refodd, gybuf);
  k5_colscan<<<dim3(256), dim3(256), 0, stream>>>(refodd);
  k6_sample<<<dim3(65536), dim3(256), 0, stream>>>(refodd, gybuf, hi, out);
}

// Round 3
// 1077.127 us; speedup vs baseline: 1.0032x; 1.0032x over previous
//
#include <hip/hip_runtime.h>
#include <math.h>

#define N_IMG 16
#define CIN   64
#define CMID  128
#define CO    32
#define KHD   16
#define HL    128
#define WL    128
#define HO    256
#define WO    256
#define EPSV  1e-5f

// ---------------- workspace layout (floats) ----------------
// [0, 33554432)            t (16,128,128,128)       -- dead after K3
// [33554432, 50331648)     refodd (16,16,256,256)   -- read-only in K56
// [50331648, +2048)        S1
// [+2048, +2048)           S2
// [+..., 65536)            w2effT (16,128,32)  [n][c][o]
// [+..., 512)              beff (16,32)
// total 50,401,744 floats = 201.6 MB
// gy lives in d_out (K56 reads gy[idx] before writing out[idx] in-thread).

// K1: t[n][o][y][x] = conv1_b[o] + sum_c conv1_w[o][c] * lo[n][c][y][x]
__global__ __launch_bounds__(256) void k1_conv1(const float* __restrict__ lo,
                                                const float* __restrict__ w1,
                                                const float* __restrict__ b1,
                                                float* __restrict__ t) {
  int blk = blockIdx.x;        // n*128 + y
  int n = blk >> 7, y = blk & 127;
  __shared__ float lo_l[CIN * WL];    // [c][x]  32 KB
  __shared__ float w1_l[CMID * CIN];  // [o][c]  32 KB
  int tid = threadIdx.x;
  const float* lo_base = lo + (size_t)n * CIN * (HL * WL) + y * WL;
  for (int f = tid; f < CIN * WL / 4; f += 256) {
    int c = f >> 5, xi = f & 31;
    ((float4*)lo_l)[f] = *(const float4*)(lo_base + (size_t)c * (HL * WL) + xi * 4);
  }
  for (int f = tid; f < CMID * CIN / 4; f += 256)
    ((float4*)w1_l)[f] = ((const float4*)w1)[f];
  __syncthreads();

  int pg = tid & 31, og = tid >> 5;  // 32 pixel-groups(x4) x 8 out-groups(x16)
  float acc[16][4];
#pragma unroll
  for (int oo = 0; oo < 16; ++oo)
    acc[oo][0] = acc[oo][1] = acc[oo][2] = acc[oo][3] = 0.f;

  for (int c = 0; c < CIN; c += 4) {
    float4 v0 = *(float4*)&lo_l[(c + 0) * WL + pg * 4];
    float4 v1 = *(float4*)&lo_l[(c + 1) * WL + pg * 4];
    float4 v2 = *(float4*)&lo_l[(c + 2) * WL + pg * 4];
    float4 v3 = *(float4*)&lo_l[(c + 3) * WL + pg * 4];
#pragma unroll
    for (int oo = 0; oo < 16; ++oo) {
      float4 w = *(float4*)&w1_l[(og * 16 + oo) * CIN + c];
      acc[oo][0] += w.x * v0.x + w.y * v1.x + w.z * v2.x + w.w * v3.x;
      acc[oo][1] += w.x * v0.y + w.y * v1.y + w.z * v2.y + w.w * v3.y;
      acc[oo][2] += w.x * v0.z + w.y * v1.z + w.z * v2.z + w.w * v3.z;
      acc[oo][3] += w.x * v0.w + w.y * v1.w + w.z * v2.w + w.w * v3.w;
    }
  }
#pragma unroll
  for (int oo = 0; oo < 16; ++oo) {
    int o = og * 16 + oo;
    float bb = b1[o];
    float4 r;
    r.x = acc[oo][0] + bb; r.y = acc[oo][1] + bb;
    r.z = acc[oo][2] + bb; r.w = acc[oo][3] + bb;
    *(float4*)(t + (((size_t)n * CMID + o) * HL + y) * WL + pg * 4) = r;
  }
}

__device__ __forceinline__ float gelu_exact(float v) {
  return 0.5f * v * (1.f + erff(v * 0.70710678118654752f));
}

// K2: per (n,c): sum & sumsq of GELU(bilinear_upsample(t[n,c])) over 256x256
__global__ __launch_bounds__(256) void k2_stats(const float* __restrict__ t,
                                                float* __restrict__ S1,
                                                float* __restrict__ S2) {
  int blk = blockIdx.x;  // n*128 + c
  __shared__ float img[HL * WL];  // exactly 64 KB; [0..15] reused for reduction
  int tid = threadIdx.x;
  const float* tb = t + (size_t)blk * (HL * WL);
  for (int f = tid; f < HL * WL / 4; f += 256)
    ((float4*)img)[f] = ((const float4*)tb)[f];
  __syncthreads();

  float xs = tid * (127.f / 255.f);
  float x0f = floorf(xs);
  int x0 = (int)x0f, x1 = min(x0 + 1, 127);
  float wx = xs - x0f, omwx = 1.f - wx;
  float sum = 0.f, ssq = 0.f;
  for (int i = 0; i < HO; ++i) {
    float ys = i * (127.f / 255.f);
    float y0f = floorf(ys);
    int y0 = (int)y0f, y1 = min(y0 + 1, 127);
    float wy = ys - y0f, omwy = 1.f - wy;
    float r0 = img[y0 * WL + x0] * omwx + img[y0 * WL + x1] * wx;
    float r1 = img[y1 * WL + x0] * omwx + img[y1 * WL + x1] * wx;
    float g = gelu_exact(r0 * omwy + r1 * wy);
    sum += g; ssq += g * g;
  }
  int lane = tid & 63, w = tid >> 6;
#pragma unroll
  for (int d = 32; d; d >>= 1) {
    sum += __shfl_xor(sum, d, 64);
    ssq += __shfl_xor(ssq, d, 64);
  }
  __syncthreads();  // everyone done reading img
  if (lane == 0) { img[w] = sum; img[8 + w] = ssq; }
  __syncthreads();
  if (tid == 0) {
    S1[blk] = img[0] + img[1] + img[2] + img[3];
    S2[blk] = img[8] + img[9] + img[10] + img[11];
  }
}

// K2b: fold GN + SE + conv2 into per-image effective weights (transposed [c][o]) + bias
__global__ __launch_bounds__(128) void k2b_prep(const float* __restrict__ S1,
                                                const float* __restrict__ S2,
                                                const float* __restrict__ gn_w,
                                                const float* __restrict__ gn_b,
                                                const float* __restrict__ se_w1,
                                                const float* __restrict__ se_w2,
                                                const float* __restrict__ w2,
                                                float* __restrict__ w2effT,
                                                float* __restrict__ beff) {
  int n = blockIdx.x, c = threadIdx.x;
  __shared__ float mArr[128], eArr[128], pArr[128], hArr[16], dArr[128];
  const float inv = 1.f / 65536.f;
  float m = S1[n * 128 + c] * inv, e2 = S2[n * 128 + c] * inv;
  mArr[c] = m; eArr[c] = e2;
  __syncthreads();
  int g0 = (c >> 6) << 6;
  float mu = 0.f, E2 = 0.f;
  for (int q = 0; q < 64; ++q) { mu += mArr[g0 + q]; E2 += eArr[g0 + q]; }
  mu *= (1.f / 64.f); E2 *= (1.f / 64.f);
  float var = E2 - mu * mu;
  float rs = rsqrtf(var + EPSV);
  float gw = gn_w[c], gb = gn_b[c];
  pArr[c] = (m - mu) * rs * gw + gb;
  __syncthreads();
  if (c < 16) {
    float h = 0.f;
    for (int q = 0; q < 128; ++q) h += se_w1[c * 128 + q] * pArr[q];
    hArr[c] = fmaxf(h, 0.f);
  }
  __syncthreads();
  float sacc = 0.f;
  for (int q = 0; q < 16; ++q) sacc += se_w2[c * 16 + q] * hArr[q];
  float s = 1.f / (1.f + __expf(-sacc));
  float a = s * gw * rs;
  float d = s * (gb - gw * rs * mu);
  dArr[c] = d;
  __syncthreads();
  for (int o = 0; o < 32; ++o)
    w2effT[((size_t)n * 128 + c) * 32 + o] = w2[o * 128 + c] * a;
  if (c < 32) {
    float bb = 0.f;
    for (int q = 0; q < 128; ++q) bb += w2[c * 128 + q] * dArr[q];
    beff[n * 32 + c] = bb;
  }
}

// K3: per (n, output-row i): recompute r = GELU(upsample(t)), acc = W2eff . r + beff,
//     then row softmax+cumsum of even channels -> gy (in d_out); odd channels -> refodd
// Weights/bias read via wave-uniform global addresses -> scalar loads (no LDS/VALU cost).
__global__ __launch_bounds__(256) void k3_ref(const float* __restrict__ t,
                                              const float* __restrict__ w2effT,
                                              const float* __restrict__ beff,
                                              float* __restrict__ refodd,
                                              float* __restrict__ gy) {
  int blk = blockIdx.x;  // n*256 + i
  int n = blk >> 8, i = blk & 255;
  __shared__ float ch[32 * 2 * WL];     // [cc][row][x] 32 KB
  __shared__ float sred[4], ssum[4];
  int tid = threadIdx.x;
  const float* wn = w2effT + (size_t)n * CMID * CO;  // uniform base
  const float* bn = beff + n * CO;                   // uniform base

  float ys = i * (127.f / 255.f);
  float y0f = floorf(ys);
  int y0 = (int)y0f, y1 = min(y0 + 1, 127);
  float wy = ys - y0f, omwy = 1.f - wy;
  float xs = tid * (127.f / 255.f);
  float x0f = floorf(xs);
  int x0 = (int)x0f, x1 = min(x0 + 1, 127);
  float wx = xs - x0f, omwx = 1.f - wx;

  float acc[32];
#pragma unroll
  for (int o = 0; o < 32; ++o) acc[o] = 0.f;

  const size_t tbase = (size_t)n * CMID * (HL * WL);
  for (int cb = 0; cb < 4; ++cb) {
    __syncthreads();
    for (int f = tid; f < 32 * 2 * WL / 4; f += 256) {
      int cc = f >> 6, rem = f & 63;
      int row = rem >> 5, xi = rem & 31;
      int yy = row ? y1 : y0;
      ((float4*)ch)[f] =
          *(const float4*)(t + tbase + ((size_t)(cb * 32 + cc) * HL + yy) * WL + xi * 4);
    }
    __syncthreads();
#pragma unroll 4
    for (int cc = 0; cc < 32; ++cc) {
      const float* c0 = &ch[cc * 2 * WL];
      float v0 = c0[x0] * omwx + c0[x1] * wx;
      float v1 = c0[WL + x0] * omwx + c0[WL + x1] * wx;
      float g = gelu_exact(v0 * omwy + v1 * wy);
      const float* wrow = wn + (cb * 32 + cc) * CO;  // uniform -> s_load
#pragma unroll
      for (int o4 = 0; o4 < 8; ++o4) {
        float4 w4 = *(const float4*)&wrow[o4 * 4];
        acc[o4 * 4 + 0] += w4.x * g;
        acc[o4 * 4 + 1] += w4.y * g;
        acc[o4 * 4 + 2] += w4.z * g;
        acc[o4 * 4 + 3] += w4.w * g;
      }
    }
  }
#pragma unroll
  for (int o = 0; o < 32; ++o) acc[o] += bn[o];  // uniform -> s_load

  // odd channels: materialize for the column-scan kernel
#pragma unroll
  for (int k = 0; k < 16; ++k)
    refodd[(((size_t)(n * 16 + k)) * HO + i) * WO + tid] = acc[2 * k + 1];

  // even channels: row softmax + inclusive cumsum -> gy = cumsum/total * 255
  int lane = tid & 63, w = tid >> 6;
  for (int k = 0; k < 16; ++k) {
    float v = acc[2 * k];
    float m = v;
#pragma unroll
    for (int d = 32; d; d >>= 1) m = fmaxf(m, __shfl_xor(m, d, 64));
    if (lane == 0) sred[w] = m;
    __syncthreads();
    m = fmaxf(fmaxf(sred[0], sred[1]), fmaxf(sred[2], sred[3]));
    float p = __expf(v - m);
#pragma unroll
    for (int d = 1; d < 64; d <<= 1) {
      float q = __shfl_up(p, d, 64);
      if (lane >= d) p += q;
    }
    if (lane == 63) ssum[w] = p;
    __syncthreads();
    float off = 0.f, tot = 0.f;
#pragma unroll
    for (int q = 0; q < 4; ++q) {
      float x = ssum[q];
      tot += x;
      if (q < w) off += x;
    }
    gy[((size_t)(n * 16 + k) * HO + i) * WO + tid] = (p + off) / tot * 255.f;
    __syncthreads();
  }
}

// K56: fused column softmax+cumsum (gx) + grid sample.
// block = 1024 threads: c = tid>>8 (row chunk of 64), j = tid&255 (column).
// gy aliases out: each element read exactly by the thread that overwrites it.
__global__ __launch_bounds__(1024) void k56_colscan_sample(
    const float* __restrict__ refodd, const float* __restrict__ hi,
    float* out) {
  int nk = blockIdx.x;
  int tid = threadIdx.x;
  int c = tid >> 8, j = tid & 255;
  __shared__ float lmax[4][256];
  __shared__ float lsum[4][256];
  const float* img = refodd + (size_t)nk * (HO * WO) + j;

  float p[64];
  float m = -1e30f;
#pragma unroll
  for (int q = 0; q < 64; ++q) {
    p[q] = img[(size_t)(c * 64 + q) * WO];
    m = fmaxf(m, p[q]);
  }
  lmax[c][j] = m;
  __syncthreads();
  m = fmaxf(fmaxf(lmax[0][j], lmax[1][j]), fmaxf(lmax[2][j], lmax[3][j]));
  float s = 0.f;
#pragma unroll
  for (int q = 0; q < 64; ++q) {
    p[q] = __expf(p[q] - m);
    s += p[q];
  }
  lsum[c][j] = s;
  __syncthreads();
  float off = 0.f, tot = 0.f;
#pragma unroll
  for (int q = 0; q < 4; ++q) {
    float x = lsum[q][j];
    tot += x;
    if (q < c) off += x;
  }
  float inv = 255.f / tot;
  const float* himg = hi + (size_t)nk * (HO * WO);
  float run = off;
  size_t base = (size_t)nk * (HO * WO) + (size_t)(c * 64) * WO + j;
#pragma unroll 4
  for (int q = 0; q < 64; ++q) {
    run += p[q];
    float gxv = run * inv;
    size_t idx = base + (size_t)q * WO;
    float gyv = out[idx];  // gy (read before overwrite)
    float x0f = floorf(gxv), y0f = floorf(gyv);
    float wxv = gxv - x0f, wyv = gyv - y0f;
    float omwx = 1.f - wxv, omwy = 1.f - wyv;
    float r = 0.f;
#pragma unroll
    for (int cy = 0; cy < 2; ++cy) {
#pragma unroll
      for (int cx = 0; cx < 2; ++cx) {
        float xf = x0f + cx, yf = y0f + cy;
        bool valid = (xf >= 0.f) && (xf <= 255.f) && (yf >= 0.f) && (yf <= 255.f);
        float wgt = (cx ? wxv : omwx) * (cy ? wyv : omwy);
        if (valid) {
          int xi = (int)xf, yi = (int)yf;
          r += himg[yi * WO + xi] * wgt;
        }
      }
    }
    out[idx] = r;
  }
}

extern "C" void kernel_launch(void* const* d_in, const int* in_sizes, int n_in,
                              void* d_out, int out_size, void* d_ws, size_t ws_size,
                              hipStream_t stream) {
  (void)in_sizes; (void)n_in; (void)out_size; (void)ws_size;
  const float* lo  = (const float*)d_in[0];
  const float* hi  = (const float*)d_in[1];
  const float* w1  = (const float*)d_in[2];
  const float* b1  = (const float*)d_in[3];
  const float* gnw = (const float*)d_in[4];
  const float* gnb = (const float*)d_in[5];
  const float* sw1 = (const float*)d_in[6];
  const float* sw2 = (const float*)d_in[7];
  const float* w2  = (const float*)d_in[8];
  float* ws = (float*)d_ws;
  float* t       = ws;                    // 33,554,432 floats
  float* refodd  = ws + 33554432;         // 16,777,216 floats
  float* S1      = ws + 50331648;         // 2048
  float* S2      = S1 + 2048;             // 2048
  float* w2effT  = S2 + 2048;             // 65,536
  float* beff    = w2effT + 65536;        // 512
  float* out     = (float*)d_out;
  float* gybuf   = out;                   // gy aliases d_out (read-before-write in K56)

  k1_conv1<<<dim3(2048), dim3(256), 0, stream>>>(lo, w1, b1, t);
  k2_stats<<<dim3(2048), dim3(256), 0, stream>>>(t, S1, S2);
  k2b_prep<<<dim3(16), dim3(128), 0, stream>>>(S1, S2, gnw, gnb, sw1, sw2, w2, w2effT, beff);
  k3_ref<<<dim3(4096), dim3(256), 0, stream>>>(t, w2effT, beff, refodd, gybuf);
  k56_colscan_sample<<<dim3(256), dim3(1024), 0, stream>>>(refodd, hi, out);
}

// Round 4
// 860.089 us; speedup vs baseline: 1.2564x; 1.2523x over previous
//
#include <hip/hip_runtime.h>
#include <math.h>

#define N_IMG 16
#define CIN   64
#define CMID  128
#define CO    32
#define KHD   16
#define HL    128
#define WL    128
#define HO    256
#define WO    256
#define EPSV  1e-5f

// ---------------- workspace layout (floats) ----------------
// [0, 33554432)            t (16,128,128,128)       -- dead after K3
// [33554432, 50331648)     refodd (16,16,256,256)   -- K5 overwrites in place with gx
// [50331648, +8192)        S1p (4,2048)
// [+8192, +8192)           S2p (4,2048)
// [+..., 65536)            w2effT (16,128,32)  [n][c][o]
// [+..., 512)              beff (16,32)
// [+..., 8192)             w1T (64,128)  [c][o]
// total ~50.42M floats = 201.7 MB
// gy lives in d_out (K6 reads the gy tile into LDS before overwriting it).

// K0: transpose conv1 weights to [c][o] so K1 can read them wave-uniformly.
__global__ __launch_bounds__(256) void k0_transpose(const float* __restrict__ w1,
                                                    float* __restrict__ w1T) {
  int tid = threadIdx.x;
  for (int f = tid; f < CMID * CIN; f += 256) {
    int o = f >> 6, c = f & 63;
    w1T[c * CMID + o] = w1[f];
  }
}

// K1: t[n][o][y][x] = conv1_b[o] + sum_c conv1_w[o][c] * lo[n][c][y][x]
// 512 threads = 8 waves: wave -> (x-half, 32-output group); weights via s_load.
__global__ __launch_bounds__(512) void k1_conv1(const float* __restrict__ lo,
                                                const float* __restrict__ w1T,
                                                const float* __restrict__ b1,
                                                float* __restrict__ t) {
  int blk = blockIdx.x;        // n*128 + y
  int n = blk >> 7, y = blk & 127;
  __shared__ float lo_l[CIN * WL];    // [c][x]  32 KB
  int tid = threadIdx.x;
  const float* lo_base = lo + (size_t)n * CIN * (HL * WL) + y * WL;
  for (int f = tid; f < CIN * WL / 4; f += 512) {
    int c = f >> 5, xi = f & 31;
    ((float4*)lo_l)[f] = *(const float4*)(lo_base + (size_t)c * (HL * WL) + xi * 4);
  }
  __syncthreads();

  int wave = __builtin_amdgcn_readfirstlane(tid >> 6);  // force wave-uniform
  int lane = tid & 63;
  int half = wave >> 2;   // x-half: 0 -> [0,64), 1 -> [64,128)
  int og   = wave & 3;    // 32-output group
  int x = half * 64 + lane;

  float acc[32];
#pragma unroll
  for (int o = 0; o < 32; ++o) acc[o] = 0.f;

  const float* wbase = w1T + og * 32;   // [c][o], stride CMID; uniform
  for (int c = 0; c < CIN; ++c) {
    float lv = lo_l[c * WL + x];
    const float* wr = wbase + c * CMID;
#pragma unroll
    for (int o = 0; o < 32; ++o) acc[o] += wr[o] * lv;
  }
  const float* bb = b1 + og * 32;       // uniform
  float* tb = t + ((size_t)n * CMID + og * 32) * (HL * WL) + y * WL + x;
#pragma unroll
  for (int o = 0; o < 32; ++o) tb[(size_t)o * (HL * WL)] = acc[o] + bb[o];
}

// Fast erf (Abramowitz-Stegun 7.1.26, |err| <= 1.5e-7)
__device__ __forceinline__ float erf_fast(float x) {
  float ax = fabsf(x);
  float t = 1.f / (1.f + 0.3275911f * ax);
  float e = __expf(-ax * ax);
  float poly = t * (0.254829592f +
              t * (-0.284496736f +
              t * (1.421413741f +
              t * (-1.453152027f +
              t * 1.061405429f))));
  float r = 1.f - poly * e;
  return copysignf(r, x);
}

__device__ __forceinline__ float gelu_fast(float v) {
  return 0.5f * v * (1.f + erf_fast(v * 0.70710678118654752f));
}

// K2: per (q, n, c): partial sum & sumsq of GELU(bilinear_upsample(t[n,c]))
// over output rows [64q, 64q+64). Only the needed ~34 source rows go to LDS.
__global__ __launch_bounds__(256) void k2_stats(const float* __restrict__ t,
                                                float* __restrict__ S1p,
                                                float* __restrict__ S2p) {
  int blk = blockIdx.x;          // q*2048 + nc
  int nc = blk & 2047, q = blk >> 11;
  __shared__ float img[34 * WL]; // 17 KB
  __shared__ float red[16];
  int tid = threadIdx.x;
  int i0 = q * 64;
  int ylo = (int)floorf(i0 * (127.f / 255.f));
  int yhi = min((int)floorf((i0 + 63) * (127.f / 255.f)) + 1, 127);
  int nr = yhi - ylo + 1;
  const float* tb = t + (size_t)nc * (HL * WL) + ylo * WL;
  for (int f = tid; f < nr * (WL / 4); f += 256)
    ((float4*)img)[f] = ((const float4*)tb)[f];
  __syncthreads();

  float xs = tid * (127.f / 255.f);
  float x0f = floorf(xs);
  int x0 = (int)x0f, x1 = min(x0 + 1, 127);
  float wx = xs - x0f, omwx = 1.f - wx;
  float sum = 0.f, ssq = 0.f;
  for (int k = 0; k < 64; ++k) {
    float ys = (i0 + k) * (127.f / 255.f);
    float y0f = floorf(ys);
    int y0 = (int)y0f - ylo, y1 = min((int)y0f + 1, 127) - ylo;
    float wy = ys - y0f, omwy = 1.f - wy;
    float r0 = img[y0 * WL + x0] * omwx + img[y0 * WL + x1] * wx;
    float r1 = img[y1 * WL + x0] * omwx + img[y1 * WL + x1] * wx;
    float g = gelu_fast(r0 * omwy + r1 * wy);
    sum += g; ssq += g * g;
  }
  int lane = tid & 63, w = tid >> 6;
#pragma unroll
  for (int d = 32; d; d >>= 1) {
    sum += __shfl_xor(sum, d, 64);
    ssq += __shfl_xor(ssq, d, 64);
  }
  if (lane == 0) { red[w] = sum; red[8 + w] = ssq; }
  __syncthreads();
  if (tid == 0) {
    S1p[blk] = red[0] + red[1] + red[2] + red[3];
    S2p[blk] = red[8] + red[9] + red[10] + red[11];
  }
}

// K2b: fold GN + SE + conv2 into per-image effective weights + bias
__global__ __launch_bounds__(128) void k2b_prep(const float* __restrict__ S1p,
                                                const float* __restrict__ S2p,
                                                const float* __restrict__ gn_w,
                                                const float* __restrict__ gn_b,
                                                const float* __restrict__ se_w1,
                                                const float* __restrict__ se_w2,
                                                const float* __restrict__ w2,
                                                float* __restrict__ w2effT,
                                                float* __restrict__ beff) {
  int n = blockIdx.x, c = threadIdx.x;
  int nc = n * 128 + c;
  __shared__ float mArr[128], eArr[128], pArr[128], hArr[16], dArr[128];
  const float inv = 1.f / 65536.f;
  float m  = (S1p[nc] + S1p[2048 + nc] + S1p[4096 + nc] + S1p[6144 + nc]) * inv;
  float e2 = (S2p[nc] + S2p[2048 + nc] + S2p[4096 + nc] + S2p[6144 + nc]) * inv;
  mArr[c] = m; eArr[c] = e2;
  __syncthreads();
  int g0 = (c >> 6) << 6;
  float mu = 0.f, E2 = 0.f;
  for (int q = 0; q < 64; ++q) { mu += mArr[g0 + q]; E2 += eArr[g0 + q]; }
  mu *= (1.f / 64.f); E2 *= (1.f / 64.f);
  float var = E2 - mu * mu;
  float rs = rsqrtf(var + EPSV);
  float gw = gn_w[c], gb = gn_b[c];
  pArr[c] = (m - mu) * rs * gw + gb;
  __syncthreads();
  if (c < 16) {
    float h = 0.f;
    for (int q = 0; q < 128; ++q) h += se_w1[c * 128 + q] * pArr[q];
    hArr[c] = fmaxf(h, 0.f);
  }
  __syncthreads();
  float sacc = 0.f;
  for (int q = 0; q < 16; ++q) sacc += se_w2[c * 16 + q] * hArr[q];
  float s = 1.f / (1.f + __expf(-sacc));
  float a = s * gw * rs;
  float d = s * (gb - gw * rs * mu);
  dArr[c] = d;
  __syncthreads();
  for (int o = 0; o < 32; ++o)
    w2effT[((size_t)n * 128 + c) * 32 + o] = w2[o * 128 + c] * a;
  if (c < 32) {
    float bb = 0.f;
    for (int q = 0; q < 128; ++q) bb += w2[c * 128 + q] * dArr[q];
    beff[n * 32 + c] = bb;
  }
}

// K3: per (n, output-row i): recompute r = GELU(upsample(t)), acc = W2eff . r + beff,
//     row softmax+cumsum of even channels -> gy (in d_out); odd channels -> refodd.
__global__ __launch_bounds__(256) void k3_ref(const float* __restrict__ t,
                                              const float* __restrict__ w2effT,
                                              const float* __restrict__ beff,
                                              float* __restrict__ refodd,
                                              float* __restrict__ gy) {
  int blk = blockIdx.x;  // n*256 + i
  int n = blk >> 8, i = blk & 255;
  __shared__ float ch[32 * 2 * WL];     // [cc][row][x] 32 KB
  __shared__ float sred[4], ssum[4];
  int tid = threadIdx.x;
  const float* wn = w2effT + (size_t)n * CMID * CO;  // uniform base
  const float* bn = beff + n * CO;                   // uniform base

  float ys = i * (127.f / 255.f);
  float y0f = floorf(ys);
  int y0 = (int)y0f, y1 = min(y0 + 1, 127);
  float wy = ys - y0f, omwy = 1.f - wy;
  float xs = tid * (127.f / 255.f);
  float x0f = floorf(xs);
  int x0 = (int)x0f, x1 = min(x0 + 1, 127);
  float wx = xs - x0f, omwx = 1.f - wx;

  float acc[32];
#pragma unroll
  for (int o = 0; o < 32; ++o) acc[o] = 0.f;

  const size_t tbase = (size_t)n * CMID * (HL * WL);
  for (int cb = 0; cb < 4; ++cb) {
    __syncthreads();
    for (int f = tid; f < 32 * 2 * WL / 4; f += 256) {
      int cc = f >> 6, rem = f & 63;
      int row = rem >> 5, xi = rem & 31;
      int yy = row ? y1 : y0;
      ((float4*)ch)[f] =
          *(const float4*)(t + tbase + ((size_t)(cb * 32 + cc) * HL + yy) * WL + xi * 4);
    }
    __syncthreads();
#pragma unroll 4
    for (int cc = 0; cc < 32; ++cc) {
      const float* c0 = &ch[cc * 2 * WL];
      float v0 = c0[x0] * omwx + c0[x1] * wx;
      float v1 = c0[WL + x0] * omwx + c0[WL + x1] * wx;
      float g = gelu_fast(v0 * omwy + v1 * wy);
      const float* wrow = wn + (cb * 32 + cc) * CO;  // uniform -> s_load
#pragma unroll
      for (int o4 = 0; o4 < 8; ++o4) {
        float4 w4 = *(const float4*)&wrow[o4 * 4];
        acc[o4 * 4 + 0] += w4.x * g;
        acc[o4 * 4 + 1] += w4.y * g;
        acc[o4 * 4 + 2] += w4.z * g;
        acc[o4 * 4 + 3] += w4.w * g;
      }
    }
  }
#pragma unroll
  for (int o = 0; o < 32; ++o) acc[o] += bn[o];

  // odd channels -> refodd
#pragma unroll
  for (int k = 0; k < 16; ++k)
    refodd[(((size_t)(n * 16 + k)) * HO + i) * WO + tid] = acc[2 * k + 1];

  // even channels: row softmax + inclusive cumsum -> gy
  int lane = tid & 63, w = tid >> 6;
#pragma unroll
  for (int k = 0; k < 16; ++k) {
    float v = acc[2 * k];
    float m = v;
#pragma unroll
    for (int d = 32; d; d >>= 1) m = fmaxf(m, __shfl_xor(m, d, 64));
    if (lane == 0) sred[w] = m;
    __syncthreads();
    m = fmaxf(fmaxf(sred[0], sred[1]), fmaxf(sred[2], sred[3]));
    float p = __expf(v - m);
#pragma unroll
    for (int d = 1; d < 64; d <<= 1) {
      float q = __shfl_up(p, d, 64);
      if (lane >= d) p += q;
    }
    if (lane == 63) ssum[w] = p;
    __syncthreads();
    float off = 0.f, tot = 0.f;
#pragma unroll
    for (int q = 0; q < 4; ++q) {
      float x = ssum[q];
      tot += x;
      if (q < w) off += x;
    }
    gy[((size_t)(n * 16 + k) * HO + i) * WO + tid] = (p + off) / tot * 255.f;
    __syncthreads();
  }
}

// K5: column softmax+cumsum -> gx, in place over refodd.
// Block = (nk, 64-column slab); 256 threads = 4 row-chunks x 64 columns.
// ALL p[] loops fully unrolled (runtime index would spill p[] to scratch).
__global__ __launch_bounds__(256) void k5_colscan(float* __restrict__ refodd) {
  int blk = blockIdx.x;           // nk*4 + cg
  int nk = blk >> 2, cg = blk & 3;
  int tid = threadIdx.x;
  int c = tid >> 6, j = tid & 63;
  __shared__ float lmax[4 * 64], lsum[4 * 64];
  float* img = refodd + (size_t)nk * (HO * WO) + cg * 64 + j;

  float p[64];
  float m = -1e30f;
#pragma unroll
  for (int q = 0; q < 64; ++q) {
    p[q] = img[(size_t)(c * 64 + q) * WO];
    m = fmaxf(m, p[q]);
  }
  lmax[c * 64 + j] = m;
  __syncthreads();
  m = fmaxf(fmaxf(lmax[j], lmax[64 + j]), fmaxf(lmax[128 + j], lmax[192 + j]));
  float s = 0.f;
#pragma unroll
  for (int q = 0; q < 64; ++q) {
    p[q] = __expf(p[q] - m);
    s += p[q];
  }
  lsum[c * 64 + j] = s;
  __syncthreads();
  float off = 0.f, tot = 0.f;
#pragma unroll
  for (int q2 = 0; q2 < 4; ++q2) {
    float x = lsum[q2 * 64 + j];
    tot += x;
    if (q2 < c) off += x;
  }
  float inv255 = 255.f / tot;
  float run = off;
#pragma unroll
  for (int q = 0; q < 64; ++q) {
    run += p[q];
    img[(size_t)(c * 64 + q) * WO] = run * inv255;
  }
}

// K6: tiled grid-sample. 64x64 output tiles; coords staged in LDS (pad 65);
// gather phase maps lanes -> i (x-coord ~ ramp in i => coalesced gathers);
// result transposed back through LDS for coalesced writes. gy aliases out.
__global__ __launch_bounds__(256) void k6_sample_tiled(const float* __restrict__ gx,
                                                       const float* __restrict__ hi,
                                                       float* out) {
  int blk = blockIdx.x;            // nk*16 + ti*4 + tj
  int nk = blk >> 4, ti = (blk >> 2) & 3, tj = blk & 3;
  __shared__ float gxl[64 * 65];   // becomes result in place
  __shared__ float gyl[64 * 65];
  int tid = threadIdx.x;
  const size_t ibase = (size_t)nk * (HO * WO);
  const size_t tb = ibase + (size_t)(ti * 64) * WO + tj * 64;

  // phase A: stage coord tiles (coalesced float4 reads, scalar LDS writes)
#pragma unroll
  for (int ph = 0; ph < 4; ++ph) {
    int r = ph * 16 + (tid >> 4), c4 = (tid & 15) * 4;
    float4 vx = *(const float4*)(gx + tb + (size_t)r * WO + c4);
    float4 vy = *(const float4*)(out + tb + (size_t)r * WO + c4);
    int a = r * 65 + c4;
    gxl[a] = vx.x; gxl[a + 1] = vx.y; gxl[a + 2] = vx.z; gxl[a + 3] = vx.w;
    gyl[a] = vy.x; gyl[a + 1] = vy.y; gyl[a + 2] = vy.z; gyl[a + 3] = vy.w;
  }
  __syncthreads();

  // phase B: lanes run along i; each thread does 16 consecutive-ish j
  int il = tid & 63, jg = tid >> 6;
  const float* himg = hi + ibase;
  for (int s = 0; s < 16; ++s) {
    int j = (jg << 4) + s;
    int a = il * 65 + j;                // bank (il+j)%32: 2-way, free
    float gxv = gxl[a], gyv = gyl[a];
    float x0f = floorf(gxv), y0f = floorf(gyv);
    float wxv = gxv - x0f, wyv = gyv - y0f;
    float omwx = 1.f - wxv, omwy = 1.f - wyv;
    float r = 0.f;
#pragma unroll
    for (int cy = 0; cy < 2; ++cy) {
#pragma unroll
      for (int cx = 0; cx < 2; ++cx) {
        float xf = x0f + cx, yf = y0f + cy;
        bool valid = (xf >= 0.f) && (xf <= 255.f) && (yf >= 0.f) && (yf <= 255.f);
        float wgt = (cx ? wxv : omwx) * (cy ? wyv : omwy);
        if (valid) {
          int xi = (int)xf, yi = (int)yf;
          r += himg[yi * WO + xi] * wgt;
        }
      }
    }
    gxl[a] = r;   // in place: this element is only ever touched by this thread
  }
  __syncthreads();

  // phase C: coalesced float4 writes
#pragma unroll
  for (int ph = 0; ph < 4; ++ph) {
    int r = ph * 16 + (tid >> 4), c4 = (tid & 15) * 4;
    int a = r * 65 + c4;
    float4 v;
    v.x = gxl[a]; v.y = gxl[a + 1]; v.z = gxl[a + 2]; v.w = gxl[a + 3];
    *(float4*)(out + tb + (size_t)r * WO + c4) = v;
  }
}

extern "C" void kernel_launch(void* const* d_in, const int* in_sizes, int n_in,
                              void* d_out, int out_size, void* d_ws, size_t ws_size,
                              hipStream_t stream) {
  (void)in_sizes; (void)n_in; (void)out_size; (void)ws_size;
  const float* lo  = (const float*)d_in[0];
  const float* hi  = (const float*)d_in[1];
  const float* w1  = (const float*)d_in[2];
  const float* b1  = (const float*)d_in[3];
  const float* gnw = (const float*)d_in[4];
  const float* gnb = (const float*)d_in[5];
  const float* sw1 = (const float*)d_in[6];
  const float* sw2 = (const float*)d_in[7];
  const float* w2  = (const float*)d_in[8];
  float* ws = (float*)d_ws;
  float* t       = ws;                    // 33,554,432 floats
  float* refodd  = ws + 33554432;         // 16,777,216 floats (becomes gx in place)
  float* S1p     = ws + 50331648;         // 8192
  float* S2p     = S1p + 8192;            // 8192
  float* w2effT  = S2p + 8192;            // 65,536
  float* beff    = w2effT + 65536;        // 512
  float* w1T     = beff + 512;            // 8192
  float* out     = (float*)d_out;
  float* gybuf   = out;                   // gy aliases d_out

  k0_transpose<<<dim3(1), dim3(256), 0, stream>>>(w1, w1T);
  k1_conv1<<<dim3(2048), dim3(512), 0, stream>>>(lo, w1T, b1, t);
  k2_stats<<<dim3(8192), dim3(256), 0, stream>>>(t, S1p, S2p);
  k2b_prep<<<dim3(16), dim3(128), 0, stream>>>(S1p, S2p, gnw, gnb, sw1, sw2, w2, w2effT, beff);
  k3_ref<<<dim3(4096), dim3(256), 0, stream>>>(t, w2effT, beff, refodd, gybuf);
  k5_colscan<<<dim3(1024), dim3(256), 0, stream>>>(refodd);
  k6_sample_tiled<<<dim3(4096), dim3(256), 0, stream>>>(refodd, hi, out);
}

// Round 5
// 745.259 us; speedup vs baseline: 1.4500x; 1.1541x over previous
//
#include <hip/hip_runtime.h>
#include <math.h>

#define N_IMG 16
#define CIN   64
#define CMID  128
#define CO    32
#define KHD   16
#define HL    128
#define WL    128
#define HO    256
#define WO    256
#define EPSV  1e-5f

// ---------------- workspace layout (floats) ----------------
// [0, 33554432)            t (16,128,128,128)       -- dead after K3
// [33554432, 50331648)     refodd (16,16,256,256)   -- K5 overwrites in place with gx
// [50331648, +8192)        S1p (4,2048)
// [+8192, +8192)           S2p (4,2048)
// [+..., 65536)            w2effT (16,128,32)  [n][c][o]
// [+..., 512)              beff (16,32)
// [+..., 8192)             w1T (64,128)  [c][o]
// gy lives in d_out (K6 reads the gy tile into LDS before overwriting it).

// K0: transpose conv1 weights to [c][o] so K1 can read them wave-uniformly.
__global__ __launch_bounds__(256) void k0_transpose(const float* __restrict__ w1,
                                                    float* __restrict__ w1T) {
  int tid = threadIdx.x;
  for (int f = tid; f < CMID * CIN; f += 256) {
    int o = f >> 6, c = f & 63;
    w1T[c * CMID + o] = w1[f];
  }
}

// K1: t[n][o][y][x] = conv1_b[o] + sum_c conv1_w[o][c] * lo[n][c][y][x]
__global__ __launch_bounds__(512) void k1_conv1(const float* __restrict__ lo,
                                                const float* __restrict__ w1T,
                                                const float* __restrict__ b1,
                                                float* __restrict__ t) {
  int blk = blockIdx.x;        // n*128 + y
  int n = blk >> 7, y = blk & 127;
  __shared__ float lo_l[CIN * WL];    // [c][x]  32 KB
  int tid = threadIdx.x;
  const float* lo_base = lo + (size_t)n * CIN * (HL * WL) + y * WL;
  for (int f = tid; f < CIN * WL / 4; f += 512) {
    int c = f >> 5, xi = f & 31;
    ((float4*)lo_l)[f] = *(const float4*)(lo_base + (size_t)c * (HL * WL) + xi * 4);
  }
  __syncthreads();

  int wave = __builtin_amdgcn_readfirstlane(tid >> 6);  // force wave-uniform
  int lane = tid & 63;
  int half = wave >> 2;   // x-half
  int og   = wave & 3;    // 32-output group
  int x = half * 64 + lane;

  float acc[32];
#pragma unroll
  for (int o = 0; o < 32; ++o) acc[o] = 0.f;

  const float* wbase = w1T + og * 32;   // [c][o], stride CMID; uniform
  for (int c = 0; c < CIN; ++c) {
    float lv = lo_l[c * WL + x];
    const float* wr = wbase + c * CMID;
#pragma unroll
    for (int o = 0; o < 32; ++o) acc[o] += wr[o] * lv;
  }
  const float* bb = b1 + og * 32;       // uniform
  float* tb = t + ((size_t)n * CMID + og * 32) * (HL * WL) + y * WL + x;
#pragma unroll
  for (int o = 0; o < 32; ++o) tb[(size_t)o * (HL * WL)] = acc[o] + bb[o];
}

// Fast erf (A&S 7.1.26, |err| <= 1.5e-7), DIV-FREE: v_rcp instead of IEEE divide.
__device__ __forceinline__ float erf_fast(float x) {
  float ax = fabsf(x);
  float t = __builtin_amdgcn_rcpf(fmaf(0.3275911f, ax, 1.f));
  float e = __expf(-ax * ax);
  float poly = t * (0.254829592f +
              t * (-0.284496736f +
              t * (1.421413741f +
              t * (-1.453152027f +
              t * 1.061405429f))));
  float r = fmaf(-poly, e, 1.f);
  return copysignf(r, x);
}

__device__ __forceinline__ float gelu_fast(float v) {
  float h = 0.5f * v;
  return fmaf(h, erf_fast(v * 0.70710678118654752f), h);
}

// K2: per (q, n, c): partial sum & sumsq of GELU(bilinear_upsample(t[n,c]))
__global__ __launch_bounds__(256) void k2_stats(const float* __restrict__ t,
                                                float* __restrict__ S1p,
                                                float* __restrict__ S2p) {
  int blk = blockIdx.x;          // q*2048 + nc
  int nc = blk & 2047, q = blk >> 11;
  __shared__ float img[34 * WL]; // 17 KB
  __shared__ float red[16];
  int tid = threadIdx.x;
  int i0 = q * 64;
  int ylo = (int)floorf(i0 * (127.f / 255.f));
  int yhi = min((int)floorf((i0 + 63) * (127.f / 255.f)) + 1, 127);
  int nr = yhi - ylo + 1;
  const float* tb = t + (size_t)nc * (HL * WL) + ylo * WL;
  for (int f = tid; f < nr * (WL / 4); f += 256)
    ((float4*)img)[f] = ((const float4*)tb)[f];
  __syncthreads();

  float xs = tid * (127.f / 255.f);
  float x0f = floorf(xs);
  int x0 = (int)x0f, x1 = min(x0 + 1, 127);
  float wx = xs - x0f, omwx = 1.f - wx;
  float sum = 0.f, ssq = 0.f;
  for (int k = 0; k < 64; ++k) {
    float ys = (i0 + k) * (127.f / 255.f);
    float y0f = floorf(ys);
    int y0 = (int)y0f - ylo, y1 = min((int)y0f + 1, 127) - ylo;
    float wy = ys - y0f, omwy = 1.f - wy;
    float r0 = img[y0 * WL + x0] * omwx + img[y0 * WL + x1] * wx;
    float r1 = img[y1 * WL + x0] * omwx + img[y1 * WL + x1] * wx;
    float g = gelu_fast(r0 * omwy + r1 * wy);
    sum += g; ssq += g * g;
  }
  int lane = tid & 63, w = tid >> 6;
#pragma unroll
  for (int d = 32; d; d >>= 1) {
    sum += __shfl_xor(sum, d, 64);
    ssq += __shfl_xor(ssq, d, 64);
  }
  if (lane == 0) { red[w] = sum; red[8 + w] = ssq; }
  __syncthreads();
  if (tid == 0) {
    S1p[blk] = red[0] + red[1] + red[2] + red[3];
    S2p[blk] = red[8] + red[9] + red[10] + red[11];
  }
}

// K2b: fold GN + SE + conv2 into per-image effective weights + bias
__global__ __launch_bounds__(128) void k2b_prep(const float* __restrict__ S1p,
                                                const float* __restrict__ S2p,
                                                const float* __restrict__ gn_w,
                                                const float* __restrict__ gn_b,
                                                const float* __restrict__ se_w1,
                                                const float* __restrict__ se_w2,
                                                const float* __restrict__ w2,
                                                float* __restrict__ w2effT,
                                                float* __restrict__ beff) {
  int n = blockIdx.x, c = threadIdx.x;
  int nc = n * 128 + c;
  __shared__ float mArr[128], eArr[128], pArr[128], hArr[16], dArr[128];
  const float inv = 1.f / 65536.f;
  float m  = (S1p[nc] + S1p[2048 + nc] + S1p[4096 + nc] + S1p[6144 + nc]) * inv;
  float e2 = (S2p[nc] + S2p[2048 + nc] + S2p[4096 + nc] + S2p[6144 + nc]) * inv;
  mArr[c] = m; eArr[c] = e2;
  __syncthreads();
  int g0 = (c >> 6) << 6;
  float mu = 0.f, E2 = 0.f;
  for (int q = 0; q < 64; ++q) { mu += mArr[g0 + q]; E2 += eArr[g0 + q]; }
  mu *= (1.f / 64.f); E2 *= (1.f / 64.f);
  float var = E2 - mu * mu;
  float rs = rsqrtf(var + EPSV);
  float gw = gn_w[c], gb = gn_b[c];
  pArr[c] = (m - mu) * rs * gw + gb;
  __syncthreads();
  if (c < 16) {
    float h = 0.f;
    for (int q = 0; q < 128; ++q) h += se_w1[c * 128 + q] * pArr[q];
    hArr[c] = fmaxf(h, 0.f);
  }
  __syncthreads();
  float sacc = 0.f;
  for (int q = 0; q < 16; ++q) sacc += se_w2[c * 16 + q] * hArr[q];
  float s = __builtin_amdgcn_rcpf(1.f + __expf(-sacc));
  float a = s * gw * rs;
  float d = s * (gb - gw * rs * mu);
  dArr[c] = d;
  __syncthreads();
  for (int o = 0; o < 32; ++o)
    w2effT[((size_t)n * 128 + c) * 32 + o] = w2[o * 128 + c] * a;
  if (c < 32) {
    float bb = 0.f;
    for (int q = 0; q < 128; ++q) bb += w2[c * 128 + q] * dArr[q];
    beff[n * 32 + c] = bb;
  }
}

// K3: per (n, output-row i): stage y-COMBINED source rows per channel in LDS,
//     then per pixel: 1 ds_read2 + x-interp + gelu + 32 s_load-weight fmacs.
//     Row softmax+cumsum of even channels -> gy (d_out); odd -> refodd.
__global__ __launch_bounds__(256) void k3_ref(const float* __restrict__ t,
                                              const float* __restrict__ w2effT,
                                              const float* __restrict__ beff,
                                              float* __restrict__ refodd,
                                              float* __restrict__ gy) {
  int blk = blockIdx.x;  // n*256 + i
  int n = blk >> 8, i = blk & 255;
  __shared__ float ch[32 * 128 + 4];    // y-combined rows [cc][x] + NaN-guard pad
  __shared__ float lmaxS[64], lsumS[64];
  int tid = threadIdx.x;
  const float* wn = w2effT + (size_t)n * CMID * CO;  // uniform base
  const float* bn = beff + n * CO;                   // uniform base

  if (tid < 4) ch[32 * 128 + tid] = 0.f;  // pad: finite for the x0+1 read at cc=31

  float ys = i * (127.f / 255.f);
  float y0f = floorf(ys);
  int y0 = (int)y0f, y1 = min(y0 + 1, 127);
  float wy = ys - y0f, omwy = 1.f - wy;
  float xs = tid * (127.f / 255.f);
  float x0f = floorf(xs);
  int x0 = (int)x0f;
  float wx = xs - x0f, omwx = 1.f - wx;

  float acc[32];
#pragma unroll
  for (int o = 0; o < 32; ++o) acc[o] = 0.f;

  const size_t tbase = (size_t)n * CMID * (HL * WL);
  for (int cb = 0; cb < 4; ++cb) {
    __syncthreads();
    // stage: combined[cc][x] = omwy*t[y0][x] + wy*t[y1][x]
    for (int f = tid; f < 32 * 32; f += 256) {
      int cc = f >> 5, x4 = (f & 31) * 4;
      const float* base = t + tbase + (size_t)(cb * 32 + cc) * (HL * WL) + x4;
      float4 a = *(const float4*)(base + y0 * WL);
      float4 b = *(const float4*)(base + y1 * WL);
      float4 cmb;
      cmb.x = fmaf(a.x, omwy, b.x * wy);
      cmb.y = fmaf(a.y, omwy, b.y * wy);
      cmb.z = fmaf(a.z, omwy, b.z * wy);
      cmb.w = fmaf(a.w, omwy, b.w * wy);
      *(float4*)&ch[cc * 128 + x4] = cmb;
    }
    __syncthreads();
#pragma unroll 8
    for (int cc = 0; cc < 32; ++cc) {
      const float* c0 = &ch[cc * 128 + x0];
      float va = c0[0], vb = c0[1];         // ds_read2_b32
      float g = gelu_fast(fmaf(va, omwx, vb * wx));
      const float* wrow = wn + (cb * 32 + cc) * CO;  // uniform -> s_load
#pragma unroll
      for (int o4 = 0; o4 < 8; ++o4) {
        float4 w4 = *(const float4*)&wrow[o4 * 4];
        acc[o4 * 4 + 0] += w4.x * g;
        acc[o4 * 4 + 1] += w4.y * g;
        acc[o4 * 4 + 2] += w4.z * g;
        acc[o4 * 4 + 3] += w4.w * g;
      }
    }
  }
#pragma unroll
  for (int o = 0; o < 32; ++o) acc[o] += bn[o];

  // odd channels -> refodd
#pragma unroll
  for (int k = 0; k < 16; ++k)
    refodd[(((size_t)(n * 16 + k)) * HO + i) * WO + tid] = acc[2 * k + 1];

  // even channels: row softmax + cumsum -> gy. 3 barriers total (batched phases).
  int lane = tid & 63, w = tid >> 6;
  // phase 1: wave-local maxima
#pragma unroll
  for (int k = 0; k < 16; ++k) {
    float m = acc[2 * k];
#pragma unroll
    for (int d = 32; d; d >>= 1) m = fmaxf(m, __shfl_xor(m, d, 64));
    if (lane == 0) lmaxS[k * 4 + w] = m;
  }
  __syncthreads();
  // phase 2: exp + wave-local inclusive scan
  float pk[16];
#pragma unroll
  for (int k = 0; k < 16; ++k) {
    float m = fmaxf(fmaxf(lmaxS[k * 4 + 0], lmaxS[k * 4 + 1]),
                    fmaxf(lmaxS[k * 4 + 2], lmaxS[k * 4 + 3]));
    float p = __expf(acc[2 * k] - m);
#pragma unroll
    for (int d = 1; d < 64; d <<= 1) {
      float q = __shfl_up(p, d, 64);
      if (lane >= d) p += q;
    }
    pk[k] = p;
    if (lane == 63) lsumS[k * 4 + w] = p;
  }
  __syncthreads();
  // phase 3: cross-wave offset + normalize
#pragma unroll
  for (int k = 0; k < 16; ++k) {
    float off = 0.f, tot = 0.f;
#pragma unroll
    for (int q = 0; q < 4; ++q) {
      float x = lsumS[k * 4 + q];
      tot += x;
      if (q < w) off += x;
    }
    gy[((size_t)(n * 16 + k) * HO + i) * WO + tid] =
        (pk[k] + off) * (255.f * __builtin_amdgcn_rcpf(tot));
  }
}

// K5: column softmax+cumsum -> gx, in place over refodd.
__global__ __launch_bounds__(256) void k5_colscan(float* __restrict__ refodd) {
  int blk = blockIdx.x;           // nk*4 + cg
  int nk = blk >> 2, cg = blk & 3;
  int tid = threadIdx.x;
  int c = tid >> 6, j = tid & 63;
  __shared__ float lmax[4 * 64], lsum[4 * 64];
  float* img = refodd + (size_t)nk * (HO * WO) + cg * 64 + j;

  float p[64];
  float m = -1e30f;
#pragma unroll
  for (int q = 0; q < 64; ++q) {
    p[q] = img[(size_t)(c * 64 + q) * WO];
    m = fmaxf(m, p[q]);
  }
  lmax[c * 64 + j] = m;
  __syncthreads();
  m = fmaxf(fmaxf(lmax[j], lmax[64 + j]), fmaxf(lmax[128 + j], lmax[192 + j]));
  float s = 0.f;
#pragma unroll
  for (int q = 0; q < 64; ++q) {
    p[q] = __expf(p[q] - m);
    s += p[q];
  }
  lsum[c * 64 + j] = s;
  __syncthreads();
  float off = 0.f, tot = 0.f;
#pragma unroll
  for (int q2 = 0; q2 < 4; ++q2) {
    float x = lsum[q2 * 64 + j];
    tot += x;
    if (q2 < c) off += x;
  }
  float inv255 = 255.f * __builtin_amdgcn_rcpf(tot);
  float run = off;
#pragma unroll
  for (int q = 0; q < 64; ++q) {
    run += p[q];
    img[(size_t)(c * 64 + q) * WO] = run * inv255;
  }
}

// K6: tiled grid-sample (flow ~ transpose). gy aliases out.
__global__ __launch_bounds__(256) void k6_sample_tiled(const float* __restrict__ gx,
                                                       const float* __restrict__ hi,
                                                       float* out) {
  int blk = blockIdx.x;            // nk*16 + ti*4 + tj
  int nk = blk >> 4, ti = (blk >> 2) & 3, tj = blk & 3;
  __shared__ float gxl[64 * 65];   // becomes result in place
  __shared__ float gyl[64 * 65];
  int tid = threadIdx.x;
  const size_t ibase = (size_t)nk * (HO * WO);
  const size_t tb = ibase + (size_t)(ti * 64) * WO + tj * 64;

#pragma unroll
  for (int ph = 0; ph < 4; ++ph) {
    int r = ph * 16 + (tid >> 4), c4 = (tid & 15) * 4;
    float4 vx = *(const float4*)(gx + tb + (size_t)r * WO + c4);
    float4 vy = *(const float4*)(out + tb + (size_t)r * WO + c4);
    int a = r * 65 + c4;
    gxl[a] = vx.x; gxl[a + 1] = vx.y; gxl[a + 2] = vx.z; gxl[a + 3] = vx.w;
    gyl[a] = vy.x; gyl[a + 1] = vy.y; gyl[a + 2] = vy.z; gyl[a + 3] = vy.w;
  }
  __syncthreads();

  int il = tid & 63, jg = tid >> 6;
  const float* himg = hi + ibase;
  for (int s = 0; s < 16; ++s) {
    int j = (jg << 4) + s;
    int a = il * 65 + j;
    float gxv = gxl[a], gyv = gyl[a];
    float x0f = floorf(gxv), y0f = floorf(gyv);
    float wxv = gxv - x0f, wyv = gyv - y0f;
    float omwx = 1.f - wxv, omwy = 1.f - wyv;
    float r = 0.f;
#pragma unroll
    for (int cy = 0; cy < 2; ++cy) {
#pragma unroll
      for (int cx = 0; cx < 2; ++cx) {
        float xf = x0f + cx, yf = y0f + cy;
        bool valid = (xf >= 0.f) && (xf <= 255.f) && (yf >= 0.f) && (yf <= 255.f);
        float wgt = (cx ? wxv : omwx) * (cy ? wyv : omwy);
        if (valid) {
          int xi = (int)xf, yi = (int)yf;
          r += himg[yi * WO + xi] * wgt;
        }
      }
    }
    gxl[a] = r;
  }
  __syncthreads();

#pragma unroll
  for (int ph = 0; ph < 4; ++ph) {
    int r = ph * 16 + (tid >> 4), c4 = (tid & 15) * 4;
    int a = r * 65 + c4;
    float4 v;
    v.x = gxl[a]; v.y = gxl[a + 1]; v.z = gxl[a + 2]; v.w = gxl[a + 3];
    *(float4*)(out + tb + (size_t)r * WO + c4) = v;
  }
}

extern "C" void kernel_launch(void* const* d_in, const int* in_sizes, int n_in,
                              void* d_out, int out_size, void* d_ws, size_t ws_size,
                              hipStream_t stream) {
  (void)in_sizes; (void)n_in; (void)out_size; (void)ws_size;
  const float* lo  = (const float*)d_in[0];
  const float* hi  = (const float*)d_in[1];
  const float* w1  = (const float*)d_in[2];
  const float* b1  = (const float*)d_in[3];
  const float* gnw = (const float*)d_in[4];
  const float* gnb = (const float*)d_in[5];
  const float* sw1 = (const float*)d_in[6];
  const float* sw2 = (const float*)d_in[7];
  const float* w2  = (const float*)d_in[8];
  float* ws = (float*)d_ws;
  float* t       = ws;                    // 33,554,432 floats
  float* refodd  = ws + 33554432;         // 16,777,216 floats (becomes gx in place)
  float* S1p     = ws + 50331648;         // 8192
  float* S2p     = S1p + 8192;            // 8192
  float* w2effT  = S2p + 8192;            // 65,536
  float* beff    = w2effT + 65536;        // 512
  float* w1T     = beff + 512;            // 8192
  float* out     = (float*)d_out;
  float* gybuf   = out;                   // gy aliases d_out

  k0_transpose<<<dim3(1), dim3(256), 0, stream>>>(w1, w1T);
  k1_conv1<<<dim3(2048), dim3(512), 0, stream>>>(lo, w1T, b1, t);
  k2_stats<<<dim3(8192), dim3(256), 0, stream>>>(t, S1p, S2p);
  k2b_prep<<<dim3(16), dim3(128), 0, stream>>>(S1p, S2p, gnw, gnb, sw1, sw2, w2, w2effT, beff);
  k3_ref<<<dim3(4096), dim3(256), 0, stream>>>(t, w2effT, beff, refodd, gybuf);
  k5_colscan<<<dim3(1024), dim3(256), 0, stream>>>(refodd);
  k6_sample_tiled<<<dim3(4096), dim3(256), 0, stream>>>(refodd, hi, out);
}